// Round 10
// baseline (186.505 us; speedup 1.0000x reference)
//
#include <hip/hip_runtime.h>
#include <hip/hip_bf16.h>
#include <stdint.h>

// ObjectDetectionLoss (SSD MultiBox) — MI355X / gfx950
// B=64, N=16800, C=21. Output: 3 fp32 scalars.
//
// Round-10. Lessons: r2 = no hot global atomics (64 total is fine); r3 = no
// clustered LDS-atomic hist; r6 = no tid==0 serial bin-walks; r7 = no LDS
// staging convoy in K1; r9 = K1's residual is L1/TA segment throughput
// (21 scalar loads x 42 line-segments per wave ~= 24us chip-wide).
// => (a) logit rows read as 5x dwordx4 (dword-aligned unaligned-OK) + 1 dword:
//    6 vmem insts/thread instead of 21; (b) k_final fused into k_select via
//    last-block counter (rocPRIM pattern), one dispatch fewer.
//
//   K1 k_perdata (64x66 blocks, batch-aligned): sl1/ce per anchor -> ce_neg;
//      per-block pos stats (LDS, ~5 threads) -> plain float4 stores; block 0
//      zeroes the done counter for K2 (stream order makes it visible).
//   K2 k_select (64x1024): load batch values once (float4 -> LDS b128) with
//      fused 256-bin ballot-histogram; wave-parallel suffix-scan pick at every
//      level (coarse 256 + refine 256/256/128) -> exact k-th value T;
//      sum(v>T)+r*T (tie-exact fp64); LAST block reduces over batches -> out.

#define NB 64
#define NN 16800
#define NC 21
#define BPB 66                    // blocks per batch (66*256 = 16896 >= 16800)
#define NBLK1 (NB * BPB)          // 4224
#define FP32_EPS_F 1.1920928955078125e-07f

typedef float f32x4 __attribute__((ext_vector_type(4)));

// ---------------- workspace layout (bytes) — total 4,369,728 (proven-safe size)
#define OFF_PARTIAL 0u            // float4 [4224] = 67584
#define OFF_FLB     67584u        // double [64]  -> 68096
#define OFF_FLL     68096u        // double [64]  -> 68608
#define OFF_FPN     68608u        // int    [64]  -> 68864
#define OFF_DONE    68864u        // int    [1]   (+pad) -> 68928
#define OFF_CENEG   68928u        // float  [NB*NN] = 4300800 -> end 4369728

// ===================== K1: per-anchor (LDS-free hot path) =====================
__global__ __launch_bounds__(256) void k_perdata(
    const float* __restrict__ p_bboxs, const float* __restrict__ g_bboxs,
    const float* __restrict__ p_labels, const int* __restrict__ g_labels,
    const float* __restrict__ ancs,
    float* __restrict__ ce_neg, float4* __restrict__ partial,
    int* __restrict__ done)
{
    __shared__ float st[4];                    // pos, sl1, ce

    const int tid = threadIdx.x;
    const int b = blockIdx.x / BPB;
    const int j = blockIdx.x - b * BPB;
    const int nbase = j * 256;
    const int nrem = NN - nbase;
    const int nact = nrem < 256 ? nrem : 256;  // 256, or 160 for j==65
    const bool valid = tid < nact;

    if (blockIdx.x == 0 && tid == 0) *done = 0;  // for K2's last-block fusion
    if (tid < 4) st[tid] = 0.f;
    __syncthreads();                           // init before any pos-thread atomic

    if (valid) {
        const int idx = b * NN + nbase + tid;
        const float4 p = ((const float4*)p_bboxs)[idx];
        const float4 g = ((const float4*)g_bboxs)[idx];
        const float4 a = ((const float4*)ancs)[nbase + tid];
        const int gl = g_labels[idx];

        // 21-float row -> 5x dwordx4 (dword-aligned; gfx950 unaligned-global OK)
        // + 1 dword. 6 vmem insts/thread vs 21 (r9: TA segment-bound).
        const float* row = p_labels + (size_t)idx * NC;
        float x[NC];
        #pragma unroll
        for (int q = 0; q < 5; ++q) {
            f32x4 v;
            __builtin_memcpy(&v, row + 4 * q, 16);
            x[4 * q + 0] = v[0]; x[4 * q + 1] = v[1];
            x[4 * q + 2] = v[2]; x[4 * q + 3] = v[3];
        }
        x[20] = row[20];

        // regression targets + SmoothL1 (beta=1), summed over 4 coords
        const float tx = 10.0f * (g.x - a.x) / a.z;
        const float ty = 10.0f * (g.y - a.y) / a.w;
        const float tw = 5.0f * __logf(g.z / a.z);
        const float th = 5.0f * __logf(g.w / a.w);
        float sl1 = 0.f, d, ad;
        d = p.x - tx; ad = fabsf(d); sl1 += (ad < 1.f) ? 0.5f * d * d : ad - 0.5f;
        d = p.y - ty; ad = fabsf(d); sl1 += (ad < 1.f) ? 0.5f * d * d : ad - 0.5f;
        d = p.z - tw; ad = fabsf(d); sl1 += (ad < 1.f) ? 0.5f * d * d : ad - 0.5f;
        d = p.w - th; ad = fabsf(d); sl1 += (ad < 1.f) ? 0.5f * d * d : ad - 0.5f;

        // cross entropy: lse - x[gl]
        float m = x[0];
        #pragma unroll
        for (int c = 1; c < NC; ++c) m = fmaxf(m, x[c]);
        float s = 0.f;
        #pragma unroll
        for (int c = 0; c < NC; ++c) s += __expf(x[c] - m);
        const float lse = m + __logf(s);
        const float ce = fmaxf(lse - x[gl], 0.f);  // >=0 -> bits order-monotonic

        const bool pos = gl > 0;
        ce_neg[idx] = pos ? 0.f : ce;          // coalesced

        // per-block positive stats (~5 pos threads): LDS atomics only
        if (pos) {
            atomicAdd(&st[0], 1.f);
            atomicAdd(&st[1], sl1);
            atomicAdd(&st[2], ce);
        }
    }
    __syncthreads();
    if (tid == 0) partial[blockIdx.x] = make_float4(st[0], st[1], st[2], 0.f);
}

// ===================== K2: per-batch exact top-k sum + fused final =====================
__global__ __launch_bounds__(1024) void k_select(
    const float* __restrict__ ce_neg, const float4* __restrict__ partial,
    double* __restrict__ flb, double* __restrict__ fll, int* __restrict__ fpn,
    int* __restrict__ done, float* __restrict__ out)
{
    __shared__ uint4   vals4[NN / 4];          // 67200 B (16B aligned)
    __shared__ uint32_t hist[256];
    __shared__ uint32_t h2[256];
    __shared__ float s_stats[4];
    __shared__ uint32_t s_cur;
    __shared__ int s_need;
    __shared__ double dpart[16];
    __shared__ int s_last;

    uint32_t* vals = (uint32_t*)vals4;
    const int tid = threadIdx.x, lane = tid & 63, wid = tid >> 6;
    const int b = blockIdx.x;

    if (tid < 4) s_stats[tid] = 0.f;
    if (tid < 256) hist[tid] = 0u;
    __syncthreads();

    // ---- load batch values (float4), store LDS (b128), fused ballot-histogram ----
    {
        const float4* src = (const float4*)(ce_neg + (size_t)b * NN);
        for (int i = tid; i < NN / 4; i += 1024) {
            const float4 v = src[i];
            const uint4 u = make_uint4(__float_as_uint(v.x), __float_as_uint(v.y),
                                       __float_as_uint(v.z), __float_as_uint(v.w));
            vals4[i] = u;
            uint32_t comp[4] = {u.x, u.y, u.z, u.w};
            #pragma unroll
            for (int c = 0; c < 4; ++c) {
                const uint32_t dg = comp[c] >> 23;
                unsigned long long act = __ballot(true);   // active lanes
                while (act) {
                    const int leader = __ffsll((long long)act) - 1;
                    const uint32_t dl = __shfl(dg, leader);
                    const unsigned long long same = __ballot(dg == dl) & act;
                    if (lane == leader) atomicAdd(&hist[dl], (uint32_t)__popcll(same));
                    act &= ~same;
                }
            }
        }
    }

    // ---- reduce per-block stats (66 entries) ----
    if (tid < BPB) {
        const float4 p0 = partial[b * BPB + tid];
        if (p0.x != 0.f) {
            atomicAdd(&s_stats[0], p0.x);
            atomicAdd(&s_stats[1], p0.y);
            atomicAdd(&s_stats[2], p0.z);
        }
    }
    __syncthreads();

    const int pos = (int)(s_stats[0] + 0.5f);
    int k = 3 * pos;                           // NEG_RATIO
    if (k > NN) k = NN;
    if (k < 1) k = 1;                          // pos==0 masked in final

    // ---- coarse pick: wave-parallel suffix scan over 256 bins (descending) ----
    if (wid == 0) {
        uint32_t c4[4]; uint32_t cnt = 0;
        #pragma unroll
        for (int t = 0; t < 4; ++t) { c4[t] = hist[255 - (4 * lane + t)]; cnt += c4[t]; }
        uint32_t ic = cnt;
        #pragma unroll
        for (int off = 1; off < 64; off <<= 1) {
            const uint32_t tc = __shfl_up(ic, off);
            if (lane >= off) ic += tc;
        }
        const int exC = (int)(ic - cnt);
        if (exC < k && k <= (int)ic) {         // exactly one lane
            int need = k - exC;
            #pragma unroll
            for (int t = 0; t < 4; ++t) {
                const int c = (int)c4[t];
                if (need <= c) {
                    s_cur = (uint32_t)(255 - (4 * lane + t)) << 23;
                    s_need = need;
                    break;
                }
                need -= c;
            }
        }
    }
    __syncthreads();

    // ---- exact refine of 23 mantissa bits: (sh,nbins)=(15,256),(7,256),(0,128)
    #pragma unroll
    for (int p = 0; p < 3; ++p) {
        const int sh = (p == 0) ? 15 : (p == 1) ? 7 : 0;
        const uint32_t msk = (p == 0) ? 0xFF800000u : (p == 1) ? 0xFFFF8000u : 0xFFFFFF80u;
        const int per = (p == 2) ? 2 : 4;                  // bins per lane
        const uint32_t nbm1 = (p == 2) ? 127u : 255u;
        const uint32_t bm = nbm1;                          // nb-1

        if (tid < 256) h2[tid] = 0u;
        __syncthreads();
        const uint32_t cur = s_cur;
        for (int i = tid; i < NN; i += 1024) {
            const uint32_t v = vals[i];
            if ((v & msk) == cur) atomicAdd(&h2[(v >> sh) & bm], 1u);  // mantissa ~uniform
        }
        __syncthreads();
        if (wid == 0) {
            uint32_t c4[4]; uint32_t cnt = 0;
            #pragma unroll
            for (int t = 0; t < 4; ++t) {
                if (t < per) { c4[t] = h2[nbm1 - (per * lane + t)]; cnt += c4[t]; }
            }
            uint32_t ic = cnt;
            #pragma unroll
            for (int off = 1; off < 64; off <<= 1) {
                const uint32_t tc = __shfl_up(ic, off);
                if (lane >= off) ic += tc;
            }
            const int exC = (int)(ic - cnt);
            const int need_in = s_need;                    // read before write (lockstep)
            if (exC < need_in && need_in <= (int)ic) {     // exactly one lane
                int need = need_in - exC;
                #pragma unroll
                for (int t = 0; t < 4; ++t) {
                    if (t < per) {
                        const int c = (int)c4[t];
                        if (need <= c) {
                            s_cur = cur | ((nbm1 - (uint32_t)(per * lane + t)) << sh);
                            s_need = need;
                            break;
                        }
                        need -= c;
                    }
                }
            }
        }
        __syncthreads();                                   // protect next clear / final read
    }

    // ---- tie-exact top-k sum: sum(v > T) + r*T ----
    const uint32_t T = s_cur;
    const int rf = s_need;
    double loc = 0.0;
    for (int i = tid; i < NN; i += 1024) {
        const uint32_t v = vals[i];
        if (v > T) loc += (double)__uint_as_float(v);
    }
    #pragma unroll
    for (int off = 32; off > 0; off >>= 1) loc += __shfl_down(loc, off);
    if (lane == 0) dpart[wid] = loc;
    __syncthreads();

    // ---- publish per-batch results, last block reduces over B (rocPRIM pattern) ----
    if (tid == 0) {
        double tot = 0.0;
        for (int w = 0; w < 16; ++w) tot += dpart[w];
        tot += (double)rf * (double)__uint_as_float(T);
        flb[b] = (double)s_stats[1];
        fll[b] = (double)s_stats[2] + tot;
        fpn[b] = pos;
        __threadfence();                       // release: flush results device-wide
        const int old = atomicAdd(done, 1);    // 64 device atomics total (budget OK)
        s_last = (old == NB - 1) ? 1 : 0;
    }
    __syncthreads();

    if (s_last && wid == 0) {
        __threadfence();                       // acquire: invalidate before peer reads
        const double lb = flb[lane];           // lane t owns batch t (64 == NB)
        const double ll = fll[lane];
        const int pn = fpn[lane];
        const double nm = (pn > 0) ? 1.0 : 0.0;
        const float pf = fmaxf((float)pn, FP32_EPS_F);
        const double inv = nm / (double)pf;
        double tb = lb * inv;
        double tl = ll * inv;
        double tt = tb + tl;                   // COEFF = (1,1)
        #pragma unroll
        for (int off = 32; off > 0; off >>= 1) {
            tt += __shfl_down(tt, off);
            tb += __shfl_down(tb, off);
            tl += __shfl_down(tl, off);
        }
        if (lane == 0) {
            out[0] = (float)(tt / (double)NB);
            out[1] = (float)(tb / (double)NB);
            out[2] = (float)(tl / (double)NB);
        }
    }
}

// ===================== launcher =====================
extern "C" void kernel_launch(void* const* d_in, const int* in_sizes, int n_in,
                              void* d_out, int out_size, void* d_ws, size_t ws_size,
                              hipStream_t stream)
{
    const float* p_bboxs  = (const float*)d_in[0];
    const float* g_bboxs  = (const float*)d_in[1];
    const float* p_labels = (const float*)d_in[2];
    const int*   g_labels = (const int*)d_in[3];
    const float* ancs     = (const float*)d_in[4];
    float* out = (float*)d_out;

    char* ws = (char*)d_ws;
    float4* partial = (float4*)(ws + OFF_PARTIAL);
    double* flb     = (double*)(ws + OFF_FLB);
    double* fll     = (double*)(ws + OFF_FLL);
    int*    fpn     = (int*)   (ws + OFF_FPN);
    int*    done    = (int*)   (ws + OFF_DONE);
    float*  ce_neg  = (float*) (ws + OFF_CENEG);

    // no memset: done is zeroed by k_perdata block 0 (stream order), everything
    // else is written before it is read (no global accumulators)

    k_perdata<<<NBLK1, 256, 0, stream>>>(
        p_bboxs, g_bboxs, p_labels, g_labels, ancs, ce_neg, partial, done);

    k_select<<<NB, 1024, 0, stream>>>(ce_neg, partial, flb, fll, fpn, done, out);
}